// Round 17
// baseline (76.679 us; speedup 1.0000x reference)
//
#include <hip/hip_runtime.h>
#include <math.h>

// Per-batch MLP 2->36->36->36->1 (sin,sin,sin,softplus) on MFMA, round 17.
// x: (65536,2) f32; params: (32,2809) f32; out: (32,65536) f32.
//
// Formulation per 32-point tile: D = W * h^T, v_mfma_f32_32x32x16_bf16.
//   A = W (M=outfeat pad 64 -> 2 tiles), B = h^T (N=32 points),
//   bias folded at k==36 (mid layers) / k==2 (layer 1) with h=1.0.
// D layout (HW-verified): col=lane&31 (point), feat=(r&3)+8*(r>>2)+4*(lane>>5).
//
// Round-17: SIN-PIPE PROBE. r15 (more blocks) and r16 (in-wave ILP) were both
// neutral -> not latency-bound; pipe-throughput bound. 226M sins = 3459
// wave-level v_sin/SIMD; wall (111k cyc/SIMD) == 3459 x ~32cyc, i.e. the
// trans unit at ~2 lanes/cyc would BE the entire wall. Discriminate by moving
// sin to the full-rate FMA pipe: exact period-1 fold (y - rndne(y)) + odd
// Taylor deg-11 on |y|<=0.5 (max abs err 4.7e-4 << bf16 quant 2e-3).
// 9 VALU inst/sin, zero trans. Pre-committed decode:
//   dur<42: slow-trans confirmed, keep poly (hybrid split next);
//   44-48: parity (trans~16cyc), revert sin, diet VALU;
//   >50:  fast trans, revert, near issue-roofline at ~46.
// Frozen numerics otherwise: RTZ pk2 (r12), INV2PI fold (r13), plsw
// exchanges, LDS frag build, f32 final dot, softplus via __logf (r8).
// cvt_pk_bf16: condemned (r5/r6/r11). launch_bounds(256,8): condemned (r14).

#define NPTS   65536
#define NBATCH 32
#define NPAR   2809
#define ITERS  8       // points per wave = 64 * ITERS
#define INV2PI 0.15915494309189535f

typedef float        f32x16 __attribute__((ext_vector_type(16)));
typedef short        bf16x8 __attribute__((ext_vector_type(8)));
typedef unsigned int u32;
typedef unsigned int u32x2 __attribute__((ext_vector_type(2)));

// 1-inst pack {bf16_rtz(lo), bf16_rtz(hi)} (r12-proven)
static __device__ __forceinline__ u32 pk2(float lo, float hi)
{
    return __builtin_amdgcn_perm(__float_as_uint(hi), __float_as_uint(lo),
                                 0x07060302u);
}

// ROUND-17: sin(2*pi*y) on the FMA pipe. Exact period fold, then odd
// Taylor deg-11 (|x|<=0.5 rev, max abs err ~4.7e-4).
static __device__ __forceinline__ float sin_rev(float y)
{
    const float x  = y - __builtin_rintf(y);    // v_rndne + v_sub, exact
    const float t  = x * x;
    float p = fmaf(t, -15.0946426f, 42.0586940f);    // c11, c9
    p = fmaf(t, p, -76.7058598f);                     // c7
    p = fmaf(t, p,  81.6052492f);                     // c5
    p = fmaf(t, p, -41.3417022f);                     // c3
    p = fmaf(t, p,   6.28318531f);                    // c1
    return x * p;
}

// swap a's hi-32-lanes with b's lo-32-lanes (proven rounds 6-16)
static __device__ __forceinline__ u32x2 plsw(u32 a, u32 b)
{ return __builtin_amdgcn_permlane32_swap(a, b, false, false); }

static __device__ __forceinline__ bf16x8 mkfrag(u32 w0, u32 w1, u32 w2, u32 w3)
{
    union { u32 u[4]; bf16x8 v; } c;
    c.u[0] = w0; c.u[1] = w1; c.u[2] = w2; c.u[3] = w3;
    return c.v;
}
static __device__ __forceinline__ bf16x8 u4frag(uint4 u)
{ union { uint4 a; bf16x8 v; } c; c.a = u; return c.v; }

static __device__ __forceinline__ f32x16 mfma(bf16x8 a, bf16x8 b, f32x16 c)
{ return __builtin_amdgcn_mfma_f32_32x32x16_bf16(a, b, c, 0, 0, 0); }

// stable softplus; 1+t in (1,2] -> __logf exact there (round-8 proven)
static __device__ __forceinline__ float softplus(float a)
{ return fmaxf(a, 0.0f) + __logf(1.0f + __expf(-fabsf(a))); }

// ---- per-slot weight-fragment gather (r13 fold) -----------------------------

static __device__ __forceinline__ uint4 build_frag_slot(
    const float* __restrict__ pp, int f, int l)
{
    const int c31 = l & 31;
    const int g   = l >> 5;
    float tv[8];
#pragma unroll
    for (int j = 0; j < 8; ++j) tv[j] = 0.0f;

    if (f < 12) {
        const int L = f / 6, t = (f % 6) / 3, s = f % 3;
        const int wb = 108 + L * 1332;
        const int r  = c31 + 32 * t;                 // outfeat row
        if (r < 36) {
#pragma unroll
            for (int j = 0; j < 8; ++j) {
                const int i = 16 * s + 8 * g + j;    // infeat (k)
                if (i < 36)       tv[j] = pp[wb + 36 * r + i] * INV2PI;
                else if (i == 36) tv[j] = pp[wb + 1296 + r] * INV2PI;  // bias
            }
        }
    } else {
        const int t = f - 12;                        // layer-1 tile
        const int r = c31 + 32 * t;
        if (r < 36 && g == 0) {
            tv[0] = pp[2 * r]     * INV2PI;   // k=0: w_x
            tv[1] = pp[2 * r + 1] * INV2PI;   // k=1: w_y
            tv[2] = pp[72 + r]    * INV2PI;   // k=2: bias (h=1 slot)
        }
    }
    uint4 o;
    o.x = pk2(tv[0], tv[1]); o.y = pk2(tv[2], tv[3]);
    o.z = pk2(tv[4], tv[5]); o.w = pk2(tv[6], tv[7]);
    return o;
}

// ---- B-fragment builder: sin(D) -> next-layer B frag (12 words; proven) -----

static __device__ __forceinline__ void buildB(const f32x16& d1, const f32x16& d2,
                                              u32 biasw, u32 (&F)[12])
{
    float s1[16];
#pragma unroll
    for (int r = 0; r < 16; ++r) s1[r] = sin_rev(d1[r]);
    u32 c[8];
#pragma unroll
    for (int q = 0; q < 8; ++q) c[q] = pk2(s1[2 * q], s1[2 * q + 1]);
    const u32 q0 = pk2(sin_rev(d2[0]), sin_rev(d2[1]));
    const u32 q1 = pk2(sin_rev(d2[2]), sin_rev(d2[3]));

    u32x2 r;
    r = plsw(c[0], c[2]); F[0] = r.x; F[2] = r.y;   // kstep0
    r = plsw(c[1], c[3]); F[1] = r.x; F[3] = r.y;
    r = plsw(c[4], c[6]); F[4] = r.x; F[6] = r.y;   // kstep1
    r = plsw(c[5], c[7]); F[5] = r.x; F[7] = r.y;
    F[8] = q0; F[9] = q1; F[10] = biasw; F[11] = 0; // kstep2
}

// ---- BOTH point-tiles through the net, chains interleaved (r16) -------------

static __device__ __forceinline__ u32 tile_pair(
    const uint4 (&W)[12], bf16x8 w1a, bf16x8 w1b, bf16x8 blA, bf16x8 blB,
    const float (&w4a)[16], const float (&w4b)[4], float b4,
    u32 biasw, const f32x16& z)
{
    // layer 1 (K=3 in one kstep); D in revolutions
    f32x16 a1 = mfma(w1a, blA, z);
    f32x16 b1 = mfma(w1a, blB, z);
    f32x16 a2 = mfma(w1b, blA, z);
    f32x16 b2 = mfma(w1b, blB, z);

    // layer 2 (frags 0..5)
    u32 FA[12], FB[12];
    buildB(a1, a2, biasw, FA);
    buildB(b1, b2, biasw, FB);
    a1 = z; a2 = z; b1 = z; b2 = z;
#pragma unroll
    for (int s = 0; s < 3; ++s) {
        const bf16x8 fa = mkfrag(FA[4*s], FA[4*s+1], FA[4*s+2], FA[4*s+3]);
        const bf16x8 fb = mkfrag(FB[4*s], FB[4*s+1], FB[4*s+2], FB[4*s+3]);
        a1 = mfma(u4frag(W[s]),     fa, a1);
        b1 = mfma(u4frag(W[s]),     fb, b1);
        a2 = mfma(u4frag(W[3 + s]), fa, a2);
        b2 = mfma(u4frag(W[3 + s]), fb, b2);
    }

    // layer 3 (frags 6..11)
    buildB(a1, a2, biasw, FA);
    buildB(b1, b2, biasw, FB);
    a1 = z; a2 = z; b1 = z; b2 = z;
#pragma unroll
    for (int s = 0; s < 3; ++s) {
        const bf16x8 fa = mkfrag(FA[4*s], FA[4*s+1], FA[4*s+2], FA[4*s+3]);
        const bf16x8 fb = mkfrag(FB[4*s], FB[4*s+1], FB[4*s+2], FB[4*s+3]);
        a1 = mfma(u4frag(W[6 + s]), fa, a1);
        b1 = mfma(u4frag(W[6 + s]), fb, b1);
        a2 = mfma(u4frag(W[9 + s]), fa, a2);
        b2 = mfma(u4frag(W[9 + s]), fb, b2);
    }

    // final layer on VALU: sin#3 (rev) + f32 dot, both tiles interleaved
    float sA0 = 0.0f, sA1 = 0.0f, sB0 = 0.0f, sB1 = 0.0f;
#pragma unroll
    for (int r = 0; r < 16; r += 2) {
        sA0 = fmaf(w4a[r],     sin_rev(a1[r]),     sA0);
        sB0 = fmaf(w4a[r],     sin_rev(b1[r]),     sB0);
        sA1 = fmaf(w4a[r + 1], sin_rev(a1[r + 1]), sA1);
        sB1 = fmaf(w4a[r + 1], sin_rev(b1[r + 1]), sB1);
    }
#pragma unroll
    for (int r = 0; r < 4; r += 2) {
        sA0 = fmaf(w4b[r],     sin_rev(a2[r]),     sA0);
        sB0 = fmaf(w4b[r],     sin_rev(b2[r]),     sB0);
        sA1 = fmaf(w4b[r + 1], sin_rev(a2[r + 1]), sA1);
        sB1 = fmaf(w4b[r + 1], sin_rev(b2[r + 1]), sB1);
    }
    const float pA = sA0 + sA1;
    const float pB = sB0 + sB1;
    // pair-reduce: lane l (<32) adds partner l+32's partial
    const u32x2 tA = plsw(__float_as_uint(pA), __float_as_uint(pA));
    const u32x2 tB = plsw(__float_as_uint(pB), __float_as_uint(pB));
    const float spA = softplus(pA + __uint_as_float(tA.y) + b4);
    const float spB = softplus(pB + __uint_as_float(tB.y) + b4);

    // merged store word (tile A -> lanes 0..31, B -> 32..63)
    return plsw(__float_as_uint(spA), __float_as_uint(spB)).x;
}

// ---- main kernel ------------------------------------------------------------

__global__ __launch_bounds__(256) void mlp_mfma_kernel(
    const float* __restrict__ x,
    const float* __restrict__ params,     // original (32,2809)
    float* __restrict__ out)
{
    __shared__ uint4 lds_fw[14 * 64];

    const int lane = threadIdx.x & 63;
    const int wave = threadIdx.x >> 6;
    const int b    = blockIdx.y;
    const int g    = lane >> 5;

    const float* pp = params + (size_t)b * NPAR;

    // ---- phase 0: cooperative frag build into LDS (once per block) ----
#pragma unroll
    for (int k = 0; k < 4; ++k) {
        const int sid = threadIdx.x + 256 * k;   // 0..1023; 896 real slots
        if (sid < 896)
            lds_fw[sid] = build_frag_slot(pp, sid >> 6, sid & 63);
    }
    __syncthreads();

    uint4 W[12];
#pragma unroll
    for (int f = 0; f < 12; ++f)
        W[f] = lds_fw[f * 64 + lane];
    const bf16x8 w1a = u4frag(lds_fw[12 * 64 + lane]);
    const bf16x8 w1b = u4frag(lds_fw[13 * 64 + lane]);

    // ---- per-lane W4 in f32 (UNFOLDED), mapping (r&3)+8*(r>>2)+4g ----
    float w4a[16];
#pragma unroll
    for (int r = 0; r < 16; ++r)
        w4a[r] = pp[2772 + ((r & 3) + 8 * (r >> 2) + 4 * g)];
    float w4b[4];
#pragma unroll
    for (int r = 0; r < 4; ++r)
        w4b[r] = (g == 0) ? pp[2772 + 32 + r] : 0.0f;
    const float b4 = pp[2808];

    const u32 biasw = pk2(1.0f, 0.0f);

    f32x16 z;
#pragma unroll
    for (int i = 0; i < 16; ++i) z[i] = 0.0f;

#pragma unroll 1
    for (int it = 0; it < ITERS; ++it) {
        const int n = blockIdx.x * (64 * ITERS * 4) + wave * (64 * ITERS)
                    + it * 64 + lane;
        const float2 xv = reinterpret_cast<const float2*>(x)[n];

        // layer-1 B frags: own point (tile A) / partner's point (tile B).
        // g1 lanes' words sit at k-slots where W1 frag is exactly 0 -> no mask.
        const u32 pxy  = pk2(xv.x, xv.y);
        const u32 pxyB = plsw(pxy, pxy).y;

        const u32 outw = tile_pair(W, w1a, w1b,
                                   mkfrag(pxy,  biasw, 0, 0),
                                   mkfrag(pxyB, biasw, 0, 0),
                                   w4a, w4b, b4, biasw, z);

        out[(size_t)b * NPTS + n] = __uint_as_float(outw);
    }
}

extern "C" void kernel_launch(void* const* d_in, const int* in_sizes, int n_in,
                              void* d_out, int out_size, void* d_ws, size_t ws_size,
                              hipStream_t stream)
{
    const float* x = (const float*)d_in[0];
    const float* params = (const float*)d_in[1];
    float* out = (float*)d_out;

    mlp_mfma_kernel<<<dim3(NPTS / (64 * ITERS * 4), NBATCH), dim3(256), 0, stream>>>(
        x, params, out);
}

// Round 18
// 64.801 us; speedup vs baseline: 1.1833x; 1.1833x over previous
//
#include <hip/hip_runtime.h>
#include <math.h>

// Per-batch MLP 2->36->36->36->1 (sin,sin,sin,softplus) on MFMA, round 18.
// x: (65536,2) f32; params: (32,2809) f32; out: (32,65536) f32.
//
// Formulation per 32-point tile: D = W * h^T, v_mfma_f32_32x32x16_bf16.
// D layout (HW-verified): col=lane&31 (point), feat=(r&3)+8*(r>>2)+4*(lane>>5).
//
// Round-18: HYBRID SIN SPLIT. Evidence synthesis: r13(1 chain)==r16(2 chains)
// ==46.5 -> not latency-bound, a shared pipe saturated; modeled issue-sum
// (63k cyc/SIMD) < wall (111k) -> a pipe slower than modeled; r17 (all-poly,
// zero trans) = 77us VALU-bound. Unique consistent story: trans pipe at
// ~24-32 cyc/wave-v_sin (~2-3 lanes/cyc) is ~100% occupied and IS the 46us
// wall (120 sins x ~28 = 3360 = wall/iter; VALUBusy~60% excludes trans).
// Fix: route HALF the sins to the FMA pipe (r17's deg-11 poly, correctness-
// proven) and half to v_sin -> trans ~1680 + VALU ~1870 balanced -> ~31-36us
// if pipes overlap. Alternate within each burst to keep both pipes fed.
// Decode: 31-38 confirmed (tune ratio next); ~46 null (near-roofline);
// >50 revert.
// Frozen: RTZ pk2 (r12), INV2PI fold (r13), plsw exchanges, LDS frag build,
// A/B chains (r16), f32 final dot, softplus via __logf (r8).
// cvt_pk_bf16: condemned (r5/r6/r11). launch_bounds(256,8): condemned (r14).

#define NPTS   65536
#define NBATCH 32
#define NPAR   2809
#define ITERS  8       // points per wave = 64 * ITERS
#define INV2PI 0.15915494309189535f

typedef float        f32x16 __attribute__((ext_vector_type(16)));
typedef short        bf16x8 __attribute__((ext_vector_type(8)));
typedef unsigned int u32;
typedef unsigned int u32x2 __attribute__((ext_vector_type(2)));

// 1-inst pack {bf16_rtz(lo), bf16_rtz(hi)} (r12-proven)
static __device__ __forceinline__ u32 pk2(float lo, float hi)
{
    return __builtin_amdgcn_perm(__float_as_uint(hi), __float_as_uint(lo),
                                 0x07060302u);
}

// sin(2*pi*y), trans pipe (1 inst, ~24-32 cyc/wave pipe occupancy)
static __device__ __forceinline__ float sin_t(float y)
{ return __builtin_amdgcn_sinf(y); }

// sin(2*pi*y), FMA pipe (r17-proven deg-11, max abs err ~4.7e-4)
static __device__ __forceinline__ float sin_p(float y)
{
    const float x  = y - __builtin_rintf(y);    // exact period fold
    const float t  = x * x;
    float p = fmaf(t, -15.0946426f, 42.0586940f);
    p = fmaf(t, p, -76.7058598f);
    p = fmaf(t, p,  81.6052492f);
    p = fmaf(t, p, -41.3417022f);
    p = fmaf(t, p,   6.28318531f);
    return x * p;
}

// swap a's hi-32-lanes with b's lo-32-lanes (proven rounds 6-17)
static __device__ __forceinline__ u32x2 plsw(u32 a, u32 b)
{ return __builtin_amdgcn_permlane32_swap(a, b, false, false); }

static __device__ __forceinline__ bf16x8 mkfrag(u32 w0, u32 w1, u32 w2, u32 w3)
{
    union { u32 u[4]; bf16x8 v; } c;
    c.u[0] = w0; c.u[1] = w1; c.u[2] = w2; c.u[3] = w3;
    return c.v;
}
static __device__ __forceinline__ bf16x8 u4frag(uint4 u)
{ union { uint4 a; bf16x8 v; } c; c.a = u; return c.v; }

static __device__ __forceinline__ f32x16 mfma(bf16x8 a, bf16x8 b, f32x16 c)
{ return __builtin_amdgcn_mfma_f32_32x32x16_bf16(a, b, c, 0, 0, 0); }

// stable softplus; 1+t in (1,2] -> __logf exact there (round-8 proven)
static __device__ __forceinline__ float softplus(float a)
{ return fmaxf(a, 0.0f) + __logf(1.0f + __expf(-fabsf(a))); }

// ---- per-slot weight-fragment gather (r13 fold) -----------------------------

static __device__ __forceinline__ uint4 build_frag_slot(
    const float* __restrict__ pp, int f, int l)
{
    const int c31 = l & 31;
    const int g   = l >> 5;
    float tv[8];
#pragma unroll
    for (int j = 0; j < 8; ++j) tv[j] = 0.0f;

    if (f < 12) {
        const int L = f / 6, t = (f % 6) / 3, s = f % 3;
        const int wb = 108 + L * 1332;
        const int r  = c31 + 32 * t;                 // outfeat row
        if (r < 36) {
#pragma unroll
            for (int j = 0; j < 8; ++j) {
                const int i = 16 * s + 8 * g + j;    // infeat (k)
                if (i < 36)       tv[j] = pp[wb + 36 * r + i] * INV2PI;
                else if (i == 36) tv[j] = pp[wb + 1296 + r] * INV2PI;  // bias
            }
        }
    } else {
        const int t = f - 12;                        // layer-1 tile
        const int r = c31 + 32 * t;
        if (r < 36 && g == 0) {
            tv[0] = pp[2 * r]     * INV2PI;   // k=0: w_x
            tv[1] = pp[2 * r + 1] * INV2PI;   // k=1: w_y
            tv[2] = pp[72 + r]    * INV2PI;   // k=2: bias (h=1 slot)
        }
    }
    uint4 o;
    o.x = pk2(tv[0], tv[1]); o.y = pk2(tv[2], tv[3]);
    o.z = pk2(tv[4], tv[5]); o.w = pk2(tv[6], tv[7]);
    return o;
}

// ---- B-fragment builder: sin(D) -> next-layer B frag; sins split 50/50 ------

static __device__ __forceinline__ void buildB(const f32x16& d1, const f32x16& d2,
                                              u32 biasw, u32 (&F)[12])
{
    float s1[16];
#pragma unroll
    for (int r = 0; r < 16; r += 2) {
        s1[r]     = sin_t(d1[r]);       // trans pipe
        s1[r + 1] = sin_p(d1[r + 1]);   // FMA pipe
    }
    u32 c[8];
#pragma unroll
    for (int q = 0; q < 8; ++q) c[q] = pk2(s1[2 * q], s1[2 * q + 1]);
    const u32 q0 = pk2(sin_t(d2[0]), sin_p(d2[1]));
    const u32 q1 = pk2(sin_t(d2[2]), sin_p(d2[3]));

    u32x2 r;
    r = plsw(c[0], c[2]); F[0] = r.x; F[2] = r.y;   // kstep0
    r = plsw(c[1], c[3]); F[1] = r.x; F[3] = r.y;
    r = plsw(c[4], c[6]); F[4] = r.x; F[6] = r.y;   // kstep1
    r = plsw(c[5], c[7]); F[5] = r.x; F[7] = r.y;
    F[8] = q0; F[9] = q1; F[10] = biasw; F[11] = 0; // kstep2
}

// ---- BOTH point-tiles through the net, chains interleaved (r16) -------------

static __device__ __forceinline__ u32 tile_pair(
    const uint4 (&W)[12], bf16x8 w1a, bf16x8 w1b, bf16x8 blA, bf16x8 blB,
    const float (&w4a)[16], const float (&w4b)[4], float b4,
    u32 biasw, const f32x16& z)
{
    // layer 1 (K=3 in one kstep); D in revolutions
    f32x16 a1 = mfma(w1a, blA, z);
    f32x16 b1 = mfma(w1a, blB, z);
    f32x16 a2 = mfma(w1b, blA, z);
    f32x16 b2 = mfma(w1b, blB, z);

    // layer 2 (frags 0..5)
    u32 FA[12], FB[12];
    buildB(a1, a2, biasw, FA);
    buildB(b1, b2, biasw, FB);
    a1 = z; a2 = z; b1 = z; b2 = z;
#pragma unroll
    for (int s = 0; s < 3; ++s) {
        const bf16x8 fa = mkfrag(FA[4*s], FA[4*s+1], FA[4*s+2], FA[4*s+3]);
        const bf16x8 fb = mkfrag(FB[4*s], FB[4*s+1], FB[4*s+2], FB[4*s+3]);
        a1 = mfma(u4frag(W[s]),     fa, a1);
        b1 = mfma(u4frag(W[s]),     fb, b1);
        a2 = mfma(u4frag(W[3 + s]), fa, a2);
        b2 = mfma(u4frag(W[3 + s]), fb, b2);
    }

    // layer 3 (frags 6..11)
    buildB(a1, a2, biasw, FA);
    buildB(b1, b2, biasw, FB);
    a1 = z; a2 = z; b1 = z; b2 = z;
#pragma unroll
    for (int s = 0; s < 3; ++s) {
        const bf16x8 fa = mkfrag(FA[4*s], FA[4*s+1], FA[4*s+2], FA[4*s+3]);
        const bf16x8 fb = mkfrag(FB[4*s], FB[4*s+1], FB[4*s+2], FB[4*s+3]);
        a1 = mfma(u4frag(W[6 + s]), fa, a1);
        b1 = mfma(u4frag(W[6 + s]), fb, b1);
        a2 = mfma(u4frag(W[9 + s]), fa, a2);
        b2 = mfma(u4frag(W[9 + s]), fb, b2);
    }

    // final layer on VALU: sin#3 (split) + f32 dot, both tiles interleaved
    float sA0 = 0.0f, sA1 = 0.0f, sB0 = 0.0f, sB1 = 0.0f;
#pragma unroll
    for (int r = 0; r < 16; r += 2) {
        sA0 = fmaf(w4a[r],     sin_t(a1[r]),     sA0);
        sB0 = fmaf(w4a[r],     sin_t(b1[r]),     sB0);
        sA1 = fmaf(w4a[r + 1], sin_p(a1[r + 1]), sA1);
        sB1 = fmaf(w4a[r + 1], sin_p(b1[r + 1]), sB1);
    }
    {
        sA0 = fmaf(w4b[0], sin_t(a2[0]), sA0);
        sB0 = fmaf(w4b[0], sin_t(b2[0]), sB0);
        sA1 = fmaf(w4b[1], sin_p(a2[1]), sA1);
        sB1 = fmaf(w4b[1], sin_p(b2[1]), sB1);
        sA0 = fmaf(w4b[2], sin_t(a2[2]), sA0);
        sB0 = fmaf(w4b[2], sin_t(b2[2]), sB0);
        sA1 = fmaf(w4b[3], sin_p(a2[3]), sA1);
        sB1 = fmaf(w4b[3], sin_p(b2[3]), sB1);
    }
    const float pA = sA0 + sA1;
    const float pB = sB0 + sB1;
    // pair-reduce: lane l (<32) adds partner l+32's partial
    const u32x2 tA = plsw(__float_as_uint(pA), __float_as_uint(pA));
    const u32x2 tB = plsw(__float_as_uint(pB), __float_as_uint(pB));
    const float spA = softplus(pA + __uint_as_float(tA.y) + b4);
    const float spB = softplus(pB + __uint_as_float(tB.y) + b4);

    // merged store word (tile A -> lanes 0..31, B -> 32..63)
    return plsw(__float_as_uint(spA), __float_as_uint(spB)).x;
}

// ---- main kernel ------------------------------------------------------------

__global__ __launch_bounds__(256) void mlp_mfma_kernel(
    const float* __restrict__ x,
    const float* __restrict__ params,     // original (32,2809)
    float* __restrict__ out)
{
    __shared__ uint4 lds_fw[14 * 64];

    const int lane = threadIdx.x & 63;
    const int wave = threadIdx.x >> 6;
    const int b    = blockIdx.y;
    const int g    = lane >> 5;

    const float* pp = params + (size_t)b * NPAR;

    // ---- phase 0: cooperative frag build into LDS (once per block) ----
#pragma unroll
    for (int k = 0; k < 4; ++k) {
        const int sid = threadIdx.x + 256 * k;   // 0..1023; 896 real slots
        if (sid < 896)
            lds_fw[sid] = build_frag_slot(pp, sid >> 6, sid & 63);
    }
    __syncthreads();

    uint4 W[12];
#pragma unroll
    for (int f = 0; f < 12; ++f)
        W[f] = lds_fw[f * 64 + lane];
    const bf16x8 w1a = u4frag(lds_fw[12 * 64 + lane]);
    const bf16x8 w1b = u4frag(lds_fw[13 * 64 + lane]);

    // ---- per-lane W4 in f32 (UNFOLDED), mapping (r&3)+8*(r>>2)+4g ----
    float w4a[16];
#pragma unroll
    for (int r = 0; r < 16; ++r)
        w4a[r] = pp[2772 + ((r & 3) + 8 * (r >> 2) + 4 * g)];
    float w4b[4];
#pragma unroll
    for (int r = 0; r < 4; ++r)
        w4b[r] = (g == 0) ? pp[2772 + 32 + r] : 0.0f;
    const float b4 = pp[2808];

    const u32 biasw = pk2(1.0f, 0.0f);

    f32x16 z;
#pragma unroll
    for (int i = 0; i < 16; ++i) z[i] = 0.0f;

#pragma unroll 1
    for (int it = 0; it < ITERS; ++it) {
        const int n = blockIdx.x * (64 * ITERS * 4) + wave * (64 * ITERS)
                    + it * 64 + lane;
        const float2 xv = reinterpret_cast<const float2*>(x)[n];

        // layer-1 B frags: own point (tile A) / partner's point (tile B).
        const u32 pxy  = pk2(xv.x, xv.y);
        const u32 pxyB = plsw(pxy, pxy).y;

        const u32 outw = tile_pair(W, w1a, w1b,
                                   mkfrag(pxy,  biasw, 0, 0),
                                   mkfrag(pxyB, biasw, 0, 0),
                                   w4a, w4b, b4, biasw, z);

        out[(size_t)b * NPTS + n] = __uint_as_float(outw);
    }
}

extern "C" void kernel_launch(void* const* d_in, const int* in_sizes, int n_in,
                              void* d_out, int out_size, void* d_ws, size_t ws_size,
                              hipStream_t stream)
{
    const float* x = (const float*)d_in[0];
    const float* params = (const float*)d_in[1];
    float* out = (float*)d_out;

    mlp_mfma_kernel<<<dim3(NPTS / (64 * ITERS * 4), NBATCH), dim3(256), 0, stream>>>(
        x, params, out);
}

// Round 19
// 41.143 us; speedup vs baseline: 1.8637x; 1.5750x over previous
//
#include <hip/hip_runtime.h>
#include <math.h>

// Per-batch MLP 2->36->36->36->1 (sin,sin,sin,softplus) on MFMA, round 19.
// x: (65536,2) f32; params: (32,2809) f32; out: (32,65536) f32.
//
// Formulation per 32-point tile: D = W * h^T, v_mfma_f32_32x32x16_bf16.
// D layout (HW-verified): col=lane&31 (point), feat=(r&3)+8*(r>>2)+4*(lane>>5).
//
// Round-19. r18 verdict: 50/50 sin split = LINEAR MIX of all-v_sin (46.4)
// and all-poly (76.7) -> trans does NOT overlap with FMA work; v_sin and
// VALU share one issue port (v_sin ~12 cyc/wave inst, quarter-rate). Model:
// port busy 60% = 600 repack + 120x12.4 sin; the 40% idle (~1400 cyc/iter)
// is stalls. Prime suspect: x[n] load at iter top with IMMEDIATE use ->
// full L2 latency exposed per iter per wave. Changes (output bit-exact):
//  (1) ALL-v_sin restored (poly/hybrid: condemned for this net).
//  (2) x-load software pipeline: issue iter+1's load before iter's compute;
//      waitcnt lands after ~3000 cyc of compute.
//  (3) 512-thread blocks: same waves/CU, phase-0 instances halve (512
//      blocks), 8 waves co-build each LDS frag table.
// Decode: 35-41 latency theory confirmed; 44-48 intra-chain stalls -> near
// practical floor; >50 revert 512-block.
// Frozen: RTZ pk2 (r12), INV2PI fold + v_sin revolutions (r13), plsw,
// LDS frag build, A/B chains (r16), f32 final dot, softplus via __logf.
// cvt_pk_bf16: condemned. launch_bounds(256,8): condemned. poly-sin: condemned.

#define NPTS   65536
#define NBATCH 32
#define NPAR   2809
#define ITERS  8       // points per wave = 64 * ITERS
#define BLOCK  512
#define WPB    (BLOCK / 64)    // waves per block = 8
#define INV2PI 0.15915494309189535f

typedef float        f32x16 __attribute__((ext_vector_type(16)));
typedef short        bf16x8 __attribute__((ext_vector_type(8)));
typedef unsigned int u32;
typedef unsigned int u32x2 __attribute__((ext_vector_type(2)));

// 1-inst pack {bf16_rtz(lo), bf16_rtz(hi)} (r12-proven)
static __device__ __forceinline__ u32 pk2(float lo, float hi)
{
    return __builtin_amdgcn_perm(__float_as_uint(hi), __float_as_uint(lo),
                                 0x07060302u);
}

// raw v_sin_f32: sin(2*pi*y), y in revolutions (|y| <= ~0.65 here)
static __device__ __forceinline__ float sin_rev(float y)
{ return __builtin_amdgcn_sinf(y); }

// swap a's hi-32-lanes with b's lo-32-lanes (proven rounds 6-18)
static __device__ __forceinline__ u32x2 plsw(u32 a, u32 b)
{ return __builtin_amdgcn_permlane32_swap(a, b, false, false); }

static __device__ __forceinline__ bf16x8 mkfrag(u32 w0, u32 w1, u32 w2, u32 w3)
{
    union { u32 u[4]; bf16x8 v; } c;
    c.u[0] = w0; c.u[1] = w1; c.u[2] = w2; c.u[3] = w3;
    return c.v;
}
static __device__ __forceinline__ bf16x8 u4frag(uint4 u)
{ union { uint4 a; bf16x8 v; } c; c.a = u; return c.v; }

static __device__ __forceinline__ f32x16 mfma(bf16x8 a, bf16x8 b, f32x16 c)
{ return __builtin_amdgcn_mfma_f32_32x32x16_bf16(a, b, c, 0, 0, 0); }

// stable softplus; 1+t in (1,2] -> __logf exact there (round-8 proven)
static __device__ __forceinline__ float softplus(float a)
{ return fmaxf(a, 0.0f) + __logf(1.0f + __expf(-fabsf(a))); }

// ---- per-slot weight-fragment gather (r13 fold) -----------------------------

static __device__ __forceinline__ uint4 build_frag_slot(
    const float* __restrict__ pp, int f, int l)
{
    const int c31 = l & 31;
    const int g   = l >> 5;
    float tv[8];
#pragma unroll
    for (int j = 0; j < 8; ++j) tv[j] = 0.0f;

    if (f < 12) {
        const int L = f / 6, t = (f % 6) / 3, s = f % 3;
        const int wb = 108 + L * 1332;
        const int r  = c31 + 32 * t;                 // outfeat row
        if (r < 36) {
#pragma unroll
            for (int j = 0; j < 8; ++j) {
                const int i = 16 * s + 8 * g + j;    // infeat (k)
                if (i < 36)       tv[j] = pp[wb + 36 * r + i] * INV2PI;
                else if (i == 36) tv[j] = pp[wb + 1296 + r] * INV2PI;  // bias
            }
        }
    } else {
        const int t = f - 12;                        // layer-1 tile
        const int r = c31 + 32 * t;
        if (r < 36 && g == 0) {
            tv[0] = pp[2 * r]     * INV2PI;   // k=0: w_x
            tv[1] = pp[2 * r + 1] * INV2PI;   // k=1: w_y
            tv[2] = pp[72 + r]    * INV2PI;   // k=2: bias (h=1 slot)
        }
    }
    uint4 o;
    o.x = pk2(tv[0], tv[1]); o.y = pk2(tv[2], tv[3]);
    o.z = pk2(tv[4], tv[5]); o.w = pk2(tv[6], tv[7]);
    return o;
}

// ---- B-fragment builder: sin(D) -> next-layer B frag (all v_sin) ------------

static __device__ __forceinline__ void buildB(const f32x16& d1, const f32x16& d2,
                                              u32 biasw, u32 (&F)[12])
{
    float s1[16];
#pragma unroll
    for (int r = 0; r < 16; ++r) s1[r] = sin_rev(d1[r]);
    u32 c[8];
#pragma unroll
    for (int q = 0; q < 8; ++q) c[q] = pk2(s1[2 * q], s1[2 * q + 1]);
    const u32 q0 = pk2(sin_rev(d2[0]), sin_rev(d2[1]));
    const u32 q1 = pk2(sin_rev(d2[2]), sin_rev(d2[3]));

    u32x2 r;
    r = plsw(c[0], c[2]); F[0] = r.x; F[2] = r.y;   // kstep0
    r = plsw(c[1], c[3]); F[1] = r.x; F[3] = r.y;
    r = plsw(c[4], c[6]); F[4] = r.x; F[6] = r.y;   // kstep1
    r = plsw(c[5], c[7]); F[5] = r.x; F[7] = r.y;
    F[8] = q0; F[9] = q1; F[10] = biasw; F[11] = 0; // kstep2
}

// ---- BOTH point-tiles through the net, chains interleaved (r16) -------------

static __device__ __forceinline__ u32 tile_pair(
    const uint4 (&W)[12], bf16x8 w1a, bf16x8 w1b, bf16x8 blA, bf16x8 blB,
    const float (&w4a)[16], const float (&w4b)[4], float b4,
    u32 biasw, const f32x16& z)
{
    // layer 1 (K=3 in one kstep); D in revolutions
    f32x16 a1 = mfma(w1a, blA, z);
    f32x16 b1 = mfma(w1a, blB, z);
    f32x16 a2 = mfma(w1b, blA, z);
    f32x16 b2 = mfma(w1b, blB, z);

    // layer 2 (frags 0..5)
    u32 FA[12], FB[12];
    buildB(a1, a2, biasw, FA);
    buildB(b1, b2, biasw, FB);
    a1 = z; a2 = z; b1 = z; b2 = z;
#pragma unroll
    for (int s = 0; s < 3; ++s) {
        const bf16x8 fa = mkfrag(FA[4*s], FA[4*s+1], FA[4*s+2], FA[4*s+3]);
        const bf16x8 fb = mkfrag(FB[4*s], FB[4*s+1], FB[4*s+2], FB[4*s+3]);
        a1 = mfma(u4frag(W[s]),     fa, a1);
        b1 = mfma(u4frag(W[s]),     fb, b1);
        a2 = mfma(u4frag(W[3 + s]), fa, a2);
        b2 = mfma(u4frag(W[3 + s]), fb, b2);
    }

    // layer 3 (frags 6..11)
    buildB(a1, a2, biasw, FA);
    buildB(b1, b2, biasw, FB);
    a1 = z; a2 = z; b1 = z; b2 = z;
#pragma unroll
    for (int s = 0; s < 3; ++s) {
        const bf16x8 fa = mkfrag(FA[4*s], FA[4*s+1], FA[4*s+2], FA[4*s+3]);
        const bf16x8 fb = mkfrag(FB[4*s], FB[4*s+1], FB[4*s+2], FB[4*s+3]);
        a1 = mfma(u4frag(W[6 + s]), fa, a1);
        b1 = mfma(u4frag(W[6 + s]), fb, b1);
        a2 = mfma(u4frag(W[9 + s]), fa, a2);
        b2 = mfma(u4frag(W[9 + s]), fb, b2);
    }

    // final layer on VALU: sin#3 (rev) + f32 dot, both tiles interleaved
    float sA0 = 0.0f, sA1 = 0.0f, sB0 = 0.0f, sB1 = 0.0f;
#pragma unroll
    for (int r = 0; r < 16; r += 2) {
        sA0 = fmaf(w4a[r],     sin_rev(a1[r]),     sA0);
        sB0 = fmaf(w4a[r],     sin_rev(b1[r]),     sB0);
        sA1 = fmaf(w4a[r + 1], sin_rev(a1[r + 1]), sA1);
        sB1 = fmaf(w4a[r + 1], sin_rev(b1[r + 1]), sB1);
    }
#pragma unroll
    for (int r = 0; r < 4; r += 2) {
        sA0 = fmaf(w4b[r],     sin_rev(a2[r]),     sA0);
        sB0 = fmaf(w4b[r],     sin_rev(b2[r]),     sB0);
        sA1 = fmaf(w4b[r + 1], sin_rev(a2[r + 1]), sA1);
        sB1 = fmaf(w4b[r + 1], sin_rev(b2[r + 1]), sB1);
    }
    const float pA = sA0 + sA1;
    const float pB = sB0 + sB1;
    // pair-reduce: lane l (<32) adds partner l+32's partial
    const u32x2 tA = plsw(__float_as_uint(pA), __float_as_uint(pA));
    const u32x2 tB = plsw(__float_as_uint(pB), __float_as_uint(pB));
    const float spA = softplus(pA + __uint_as_float(tA.y) + b4);
    const float spB = softplus(pB + __uint_as_float(tB.y) + b4);

    // merged store word (tile A -> lanes 0..31, B -> 32..63)
    return plsw(__float_as_uint(spA), __float_as_uint(spB)).x;
}

// ---- main kernel ------------------------------------------------------------

__global__ __launch_bounds__(BLOCK) void mlp_mfma_kernel(
    const float* __restrict__ x,
    const float* __restrict__ params,     // original (32,2809)
    float* __restrict__ out)
{
    __shared__ uint4 lds_fw[14 * 64];

    const int lane = threadIdx.x & 63;
    const int wave = threadIdx.x >> 6;
    const int b    = blockIdx.y;
    const int g    = lane >> 5;

    const float* pp = params + (size_t)b * NPAR;

    // ---- phase 0: cooperative frag build into LDS (once per block) ----
#pragma unroll
    for (int k = 0; k < 2; ++k) {
        const int sid = threadIdx.x + BLOCK * k;   // 0..1023; 896 real slots
        if (sid < 896)
            lds_fw[sid] = build_frag_slot(pp, sid >> 6, sid & 63);
    }
    __syncthreads();

    uint4 W[12];
#pragma unroll
    for (int f = 0; f < 12; ++f)
        W[f] = lds_fw[f * 64 + lane];
    const bf16x8 w1a = u4frag(lds_fw[12 * 64 + lane]);
    const bf16x8 w1b = u4frag(lds_fw[13 * 64 + lane]);

    // ---- per-lane W4 in f32 (UNFOLDED), mapping (r&3)+8*(r>>2)+4g ----
    float w4a[16];
#pragma unroll
    for (int r = 0; r < 16; ++r)
        w4a[r] = pp[2772 + ((r & 3) + 8 * (r >> 2) + 4 * g)];
    float w4b[4];
#pragma unroll
    for (int r = 0; r < 4; ++r)
        w4b[r] = (g == 0) ? pp[2772 + 32 + r] : 0.0f;
    const float b4 = pp[2808];

    const u32 biasw = pk2(1.0f, 0.0f);

    f32x16 z;
#pragma unroll
    for (int i = 0; i < 16; ++i) z[i] = 0.0f;

    // ---- x-load software pipeline: iter+1's load issues before iter's use ---
    const int nbase = blockIdx.x * (64 * ITERS * WPB) + wave * (64 * ITERS) + lane;
    const float2* xp = reinterpret_cast<const float2*>(x);

    float2 xv = xp[nbase];

#pragma unroll 1
    for (int it = 0; it < ITERS; ++it) {
        // prefetch next iter's point (clamped re-load of same on last iter)
        const int itn = (it + 1 < ITERS) ? it + 1 : it;
        const float2 xvn = xp[nbase + itn * 64];

        // layer-1 B frags: own point (tile A) / partner's point (tile B).
        const u32 pxy  = pk2(xv.x, xv.y);
        const u32 pxyB = plsw(pxy, pxy).y;

        const u32 outw = tile_pair(W, w1a, w1b,
                                   mkfrag(pxy,  biasw, 0, 0),
                                   mkfrag(pxyB, biasw, 0, 0),
                                   w4a, w4b, b4, biasw, z);

        out[(size_t)b * NPTS + nbase + it * 64] = __uint_as_float(outw);
        xv = xvn;
    }
}

extern "C" void kernel_launch(void* const* d_in, const int* in_sizes, int n_in,
                              void* d_out, int out_size, void* d_ws, size_t ws_size,
                              hipStream_t stream)
{
    const float* x = (const float*)d_in[0];
    const float* params = (const float*)d_in[1];
    float* out = (float*)d_out;

    mlp_mfma_kernel<<<dim3(NPTS / (64 * ITERS * WPB), NBATCH), dim3(BLOCK), 0, stream>>>(
        x, params, out);
}